// Round 4
// baseline (309.663 us; speedup 1.0000x reference)
//
#include <hip/hip_runtime.h>

#define TSTEPS 256
#define BATCH  512
#define DIN    256
#define NROWS  (TSTEPS * BATCH)

// ---------------------------------------------------------------------------
// Kernel 1: Xproj[row][g*4+w] = theta_g[w] + sum_d x[row][d] * W_g[w][d]
// (x-dependent part of all 4 gate pre-activations, theta folded in)
// ---------------------------------------------------------------------------
__global__ __launch_bounds__(256) void xproj_kernel(
    const float* __restrict__ x,
    const float* __restrict__ Wf, const float* __restrict__ Wi,
    const float* __restrict__ Wu, const float* __restrict__ Wo,
    const float* __restrict__ thf, const float* __restrict__ thi,
    const float* __restrict__ thu, const float* __restrict__ tho,
    float* __restrict__ xp)
{
    __shared__ __align__(16) float sW[16][DIN];
    const int tid = threadIdx.x;

    // stage weights: W rows are 260 long; first 256 cols are the x-part
    for (int i = tid; i < 1024; i += 256) { int w = i >> 8, d = i & 255; sW[ 0 + w][d] = Wf[w * 260 + d]; }
    for (int i = tid; i < 1024; i += 256) { int w = i >> 8, d = i & 255; sW[ 4 + w][d] = Wi[w * 260 + d]; }
    for (int i = tid; i < 1024; i += 256) { int w = i >> 8, d = i & 255; sW[ 8 + w][d] = Wu[w * 260 + d]; }
    for (int i = tid; i < 1024; i += 256) { int w = i >> 8, d = i & 255; sW[12 + w][d] = Wo[w * 260 + d]; }
    __syncthreads();

    const int row = blockIdx.x * 256 + tid;
    const float4* xr = (const float4*)(x + (size_t)row * DIN);

    float acc[16];
    #pragma unroll
    for (int w = 0; w < 4; ++w) acc[ 0 + w] = thf[w];
    #pragma unroll
    for (int w = 0; w < 4; ++w) acc[ 4 + w] = thi[w];
    #pragma unroll
    for (int w = 0; w < 4; ++w) acc[ 8 + w] = thu[w];
    #pragma unroll
    for (int w = 0; w < 4; ++w) acc[12 + w] = tho[w];

    #pragma unroll 4
    for (int cc = 0; cc < 64; ++cc) {
        float4 xv = xr[cc];
        #pragma unroll
        for (int k = 0; k < 16; ++k) {
            float4 wv = *(const float4*)&sW[k][cc * 4];
            acc[k] = fmaf(xv.w, wv.w, fmaf(xv.z, wv.z, fmaf(xv.y, wv.y, fmaf(xv.x, wv.x, acc[k]))));
        }
    }

    float4* op = (float4*)(xp + (size_t)row * 16);
    op[0] = make_float4(acc[ 0], acc[ 1], acc[ 2], acc[ 3]);
    op[1] = make_float4(acc[ 4], acc[ 5], acc[ 6], acc[ 7]);
    op[2] = make_float4(acc[ 8], acc[ 9], acc[10], acc[11]);
    op[3] = make_float4(acc[12], acc[13], acc[14], acc[15]);
}

// ---------------------------------------------------------------------------
// Kernel 2: sequential LSTM scan. 4 lanes per batch element (one per gate),
// DPP quad_perm broadcast exchanges activated gate vectors within the quad.
// qlayer(z)[w]: products of cos(z_w) per the CNOT-ring XOR algebra.
// ---------------------------------------------------------------------------
__device__ __forceinline__ float qb0(float v) { return __int_as_float(__builtin_amdgcn_mov_dpp(__float_as_int(v), 0x00, 0xf, 0xf, true)); }
__device__ __forceinline__ float qb1(float v) { return __int_as_float(__builtin_amdgcn_mov_dpp(__float_as_int(v), 0x55, 0xf, 0xf, true)); }
__device__ __forceinline__ float qb2(float v) { return __int_as_float(__builtin_amdgcn_mov_dpp(__float_as_int(v), 0xaa, 0xf, 0xf, true)); }
__device__ __forceinline__ float qb3(float v) { return __int_as_float(__builtin_amdgcn_mov_dpp(__float_as_int(v), 0xff, 0xf, 0xf, true)); }

__device__ __forceinline__ float fast_rcp(float x) { return __builtin_amdgcn_rcpf(x); }

// sigmoid(s*x)*s + b :  s=1,b=0 -> sigmoid(x);  s=2,b=-1 -> tanh(x)
__device__ __forceinline__ float act_sb(float x, float s, float b) {
    float e = __expf(-s * x);
    return fmaf(s, fast_rcp(1.0f + e), b);
}

__device__ __forceinline__ float tanh_fast(float x) {
    float e = __expf(-2.0f * x);
    return (1.0f - e) * fast_rcp(1.0f + e);
}

__global__ __launch_bounds__(64) void recur_kernel(
    const float* __restrict__ xp,
    const float* __restrict__ Wf, const float* __restrict__ Wi,
    const float* __restrict__ Wu, const float* __restrict__ Wo,
    float* __restrict__ out)
{
    const int tid = threadIdx.x;
    const int g   = tid & 3;                   // gate: 0=f 1=i 2=u 3=o
    const int b   = blockIdx.x * 16 + (tid >> 2);

    const float* Wg = (g == 0) ? Wf : (g == 1) ? Wi : (g == 2) ? Wu : Wo;
    // recurrent 4x4 block: Wh[w][j] = Wg[w*260 + 256 + j]  (16B-aligned: 1040 = 65*16)
    const float4 w0 = *(const float4*)(Wg + 0 * 260 + 256);
    const float4 w1 = *(const float4*)(Wg + 1 * 260 + 256);
    const float4 w2 = *(const float4*)(Wg + 2 * 260 + 256);
    const float4 w3 = *(const float4*)(Wg + 3 * 260 + 256);

    const float scl = (g == 2) ? 2.0f : 1.0f;   // u-gate uses tanh = 2*sigmoid(2x)-1
    const float bia = (g == 2) ? -1.0f : 0.0f;

    float h0 = 0.f, h1 = 0.f, h2 = 0.f, h3 = 0.f;
    float c0 = 0.f, c1 = 0.f, c2 = 0.f, c3 = 0.f;

    const float4* xpv = (const float4*)xp;      // 4 float4 per row
    const int idx = b * 4 + g;                  // this lane's gate-vector slot
    float4 pre = xpv[idx];                      // prefetch t=0

    float* hx_out = out + (size_t)TSTEPS * BATCH * 4;
    float* cx_out = hx_out + BATCH * 4;

    for (int t = 0; t < TSTEPS; ++t) {
        float4 xv = pre;
        int tn = (t + 1 < TSTEPS) ? (t + 1) : t;
        pre = xpv[tn * (BATCH * 4) + idx];      // no h-dependence: fully prefetchable

        // z = x-part(+theta) + h @ Wh.T   (this lane's gate, 4 wires)
        float z0 = fmaf(h3, w0.w, fmaf(h2, w0.z, fmaf(h1, w0.y, fmaf(h0, w0.x, xv.x))));
        float z1 = fmaf(h3, w1.w, fmaf(h2, w1.z, fmaf(h1, w1.y, fmaf(h0, w1.x, xv.y))));
        float z2 = fmaf(h3, w2.w, fmaf(h2, w2.z, fmaf(h1, w2.y, fmaf(h0, w2.x, xv.z))));
        float z3 = fmaf(h3, w3.w, fmaf(h2, w3.z, fmaf(h1, w3.y, fmaf(h0, w3.x, xv.w))));

        // analytic qlayer: products of cos
        float cz0 = __cosf(z0), cz1 = __cosf(z1), cz2 = __cosf(z2), cz3 = __cosf(z3);
        float t12 = cz1 * cz2;
        float q0 = t12 * cz3;        // wire0: z1 z2 z3
        float q1 = cz0 * cz1;        // wire1: z0 z1
        float q2 = cz0 * t12;        // wire2: z0 z1 z2
        float q3 = q2  * cz3;        // wire3: z0 z1 z2 z3

        // per-gate activation (branch-free sigmoid/tanh select)
        float a0 = act_sb(q0, scl, bia);
        float a1 = act_sb(q1, scl, bia);
        float a2 = act_sb(q2, scl, bia);
        float a3 = act_sb(q3, scl, bia);

        // exchange activated gate vectors across the quad (DPP broadcasts)
        float f0 = qb0(a0), f1 = qb0(a1), f2 = qb0(a2), f3 = qb0(a3);
        float i0 = qb1(a0), i1 = qb1(a1), i2 = qb1(a2), i3 = qb1(a3);
        float u0 = qb2(a0), u1 = qb2(a1), u2 = qb2(a2), u3 = qb2(a3);
        float o0 = qb3(a0), o1 = qb3(a1), o2 = qb3(a2), o3 = qb3(a3);

        // cell / hidden update (replicated in all 4 lanes; h needed by all next step)
        c0 = fmaf(f0, c0, i0 * u0);
        c1 = fmaf(f1, c1, i1 * u1);
        c2 = fmaf(f2, c2, i2 * u2);
        c3 = fmaf(f3, c3, i3 * u3);

        h0 = o0 * tanh_fast(c0);
        h1 = o1 * tanh_fast(c1);
        h2 = o2 * tanh_fast(c2);
        h3 = o3 * tanh_fast(c3);

        // lane g stores h[g] -> coalesced contiguous wave store
        float hv = (g == 0) ? h0 : (g == 1) ? h1 : (g == 2) ? h2 : h3;
        out[t * (BATCH * 4) + b * 4 + g] = hv;
    }

    float hv = (g == 0) ? h0 : (g == 1) ? h1 : (g == 2) ? h2 : h3;
    float cv = (g == 0) ? c0 : (g == 1) ? c1 : (g == 2) ? c2 : c3;
    hx_out[b * 4 + g] = hv;
    cx_out[b * 4 + g] = cv;
}

// ---------------------------------------------------------------------------
extern "C" void kernel_launch(void* const* d_in, const int* in_sizes, int n_in,
                              void* d_out, int out_size, void* d_ws, size_t ws_size,
                              hipStream_t stream)
{
    (void)in_sizes; (void)n_in; (void)out_size; (void)ws_size;

    const float* x   = (const float*)d_in[0];
    const float* Wf  = (const float*)d_in[1];
    const float* Wi  = (const float*)d_in[2];
    const float* Wu  = (const float*)d_in[3];
    const float* Wo  = (const float*)d_in[4];
    const float* thf = (const float*)d_in[5];
    const float* thi = (const float*)d_in[6];
    const float* thu = (const float*)d_in[7];
    const float* tho = (const float*)d_in[8];

    float* xp  = (float*)d_ws;          // [NROWS][16] = 8 MiB
    float* out = (float*)d_out;         // outputs [T,B,4] ++ hx [B,4] ++ cx [B,4]

    xproj_kernel<<<NROWS / 256, 256, 0, stream>>>(x, Wf, Wi, Wu, Wo, thf, thi, thu, tho, xp);
    recur_kernel<<<BATCH / 16, 64, 0, stream>>>(xp, Wf, Wi, Wu, Wo, out);
}

// Round 8
// 286.832 us; speedup vs baseline: 1.0796x; 1.0796x over previous
//
#include <hip/hip_runtime.h>

#define TSTEPS 256
#define BATCH  512
#define DIN    256
#define NROWS  (TSTEPS * BATCH)

// ---------------------------------------------------------------------------
// Kernel 1: Xproj[row][g*4+w] = theta_g[w] + sum_d x[row][d] * W_g[w][d]
// (x-dependent part of all 4 gate pre-activations, theta folded in)
// UNCHANGED from R4 (passed verify; not yet measured — recur dominated).
// ---------------------------------------------------------------------------
__global__ __launch_bounds__(256) void xproj_kernel(
    const float* __restrict__ x,
    const float* __restrict__ Wf, const float* __restrict__ Wi,
    const float* __restrict__ Wu, const float* __restrict__ Wo,
    const float* __restrict__ thf, const float* __restrict__ thi,
    const float* __restrict__ thu, const float* __restrict__ tho,
    float* __restrict__ xp)
{
    __shared__ __align__(16) float sW[16][DIN];
    const int tid = threadIdx.x;

    for (int i = tid; i < 1024; i += 256) { int w = i >> 8, d = i & 255; sW[ 0 + w][d] = Wf[w * 260 + d]; }
    for (int i = tid; i < 1024; i += 256) { int w = i >> 8, d = i & 255; sW[ 4 + w][d] = Wi[w * 260 + d]; }
    for (int i = tid; i < 1024; i += 256) { int w = i >> 8, d = i & 255; sW[ 8 + w][d] = Wu[w * 260 + d]; }
    for (int i = tid; i < 1024; i += 256) { int w = i >> 8, d = i & 255; sW[12 + w][d] = Wo[w * 260 + d]; }
    __syncthreads();

    const int row = blockIdx.x * 256 + tid;
    const float4* xr = (const float4*)(x + (size_t)row * DIN);

    float acc[16];
    #pragma unroll
    for (int w = 0; w < 4; ++w) acc[ 0 + w] = thf[w];
    #pragma unroll
    for (int w = 0; w < 4; ++w) acc[ 4 + w] = thi[w];
    #pragma unroll
    for (int w = 0; w < 4; ++w) acc[ 8 + w] = thu[w];
    #pragma unroll
    for (int w = 0; w < 4; ++w) acc[12 + w] = tho[w];

    #pragma unroll 4
    for (int cc = 0; cc < 64; ++cc) {
        float4 xv = xr[cc];
        #pragma unroll
        for (int k = 0; k < 16; ++k) {
            float4 wv = *(const float4*)&sW[k][cc * 4];
            acc[k] = fmaf(xv.w, wv.w, fmaf(xv.z, wv.z, fmaf(xv.y, wv.y, fmaf(xv.x, wv.x, acc[k]))));
        }
    }

    float4* op = (float4*)(xp + (size_t)row * 16);
    op[0] = make_float4(acc[ 0], acc[ 1], acc[ 2], acc[ 3]);
    op[1] = make_float4(acc[ 4], acc[ 5], acc[ 6], acc[ 7]);
    op[2] = make_float4(acc[ 8], acc[ 9], acc[10], acc[11]);
    op[3] = make_float4(acc[12], acc[13], acc[14], acc[15]);
}

// ---------------------------------------------------------------------------
// Kernel 2: sequential LSTM scan. 4 lanes per batch element (one per gate),
// DPP quad_perm broadcast exchanges activated gate vectors within the quad.
// R5: 8-deep register prefetch ring (R4 counters: 853 cyc/step, VALUBusy
// 1.7% -> exposed global-load latency) + chain trees.
// R7: __exp2f -> __expf (glibc math.h macro collision broke the build;
// __expf compiled fine in R4).
// ---------------------------------------------------------------------------
__device__ __forceinline__ float qb0(float v) { return __int_as_float(__builtin_amdgcn_mov_dpp(__float_as_int(v), 0x00, 0xf, 0xf, true)); }
__device__ __forceinline__ float qb1(float v) { return __int_as_float(__builtin_amdgcn_mov_dpp(__float_as_int(v), 0x55, 0xf, 0xf, true)); }
__device__ __forceinline__ float qb2(float v) { return __int_as_float(__builtin_amdgcn_mov_dpp(__float_as_int(v), 0xaa, 0xf, 0xf, true)); }
__device__ __forceinline__ float qb3(float v) { return __int_as_float(__builtin_amdgcn_mov_dpp(__float_as_int(v), 0xff, 0xf, 0xf, true)); }

__device__ __forceinline__ float fast_rcp(float x) { return __builtin_amdgcn_rcpf(x); }

// sigmoid(s*x)*s + b :  k = -s.  s=1,b=0 -> sigmoid; s=2,b=-1 -> tanh
__device__ __forceinline__ float act_sb(float x, float k, float s, float b) {
    float e = __expf(k * x);
    return fmaf(s, fast_rcp(1.0f + e), b);
}

__device__ __forceinline__ float tanh_fast(float c) {
    float e = __expf(-2.0f * c);
    return fmaf(2.0f, fast_rcp(1.0f + e), -1.0f);
}

__global__ __launch_bounds__(64) void recur_kernel(
    const float* __restrict__ xp,
    const float* __restrict__ Wf, const float* __restrict__ Wi,
    const float* __restrict__ Wu, const float* __restrict__ Wo,
    float* __restrict__ out)
{
    const int tid = threadIdx.x;
    const int g   = tid & 3;                   // gate: 0=f 1=i 2=u 3=o
    const int b   = blockIdx.x * 16 + (tid >> 2);

    const float* Wg = (g == 0) ? Wf : (g == 1) ? Wi : (g == 2) ? Wu : Wo;
    const float4 w0 = *(const float4*)(Wg + 0 * 260 + 256);
    const float4 w1 = *(const float4*)(Wg + 1 * 260 + 256);
    const float4 w2 = *(const float4*)(Wg + 2 * 260 + 256);
    const float4 w3 = *(const float4*)(Wg + 3 * 260 + 256);

    const float scl = (g == 2) ? 2.0f : 1.0f;   // u-gate: tanh = 2*sigmoid(2x)-1
    const float bia = (g == 2) ? -1.0f : 0.0f;
    const float kk  = -scl;

    float h0 = 0.f, h1 = 0.f, h2 = 0.f, h3 = 0.f;
    float c0 = 0.f, c1 = 0.f, c2 = 0.f, c3 = 0.f;

    const float4* xpv = (const float4*)xp;      // 4 float4 per (t,b) row-slot
    const int idx = b * 4 + g;                  // this lane's gate-vector slot

    // --- 8-deep prefetch ring (static indices only -> registers) ---
    float4 buf[8];
    #pragma unroll
    for (int j = 0; j < 8; ++j) buf[j] = xpv[(size_t)j * (BATCH * 4) + idx];

    float* hx_out = out + (size_t)TSTEPS * BATCH * 4;
    float* cx_out = hx_out + BATCH * 4;

    for (int t0 = 0; t0 < TSTEPS; t0 += 8) {
        #pragma unroll
        for (int j = 0; j < 8; ++j) {
            const int t = t0 + j;
            float4 xv = buf[j];
            int tl = t + 8; tl = (tl > TSTEPS - 1) ? (TSTEPS - 1) : tl;   // clamped dup-load tail
            buf[j] = xpv[(size_t)tl * (BATCH * 4) + idx];

            // z = x-part(+theta) + h @ Wh.T  (depth-3 tree)
            float za0 = fmaf(h1, w0.y, fmaf(h0, w0.x, xv.x));
            float zb0 = fmaf(h3, w0.w, h2 * w0.z);
            float za1 = fmaf(h1, w1.y, fmaf(h0, w1.x, xv.y));
            float zb1 = fmaf(h3, w1.w, h2 * w1.z);
            float za2 = fmaf(h1, w2.y, fmaf(h0, w2.x, xv.z));
            float zb2 = fmaf(h3, w2.w, h2 * w2.z);
            float za3 = fmaf(h1, w3.y, fmaf(h0, w3.x, xv.w));
            float zb3 = fmaf(h3, w3.w, h2 * w3.z);
            float z0 = za0 + zb0, z1 = za1 + zb1, z2 = za2 + zb2, z3 = za3 + zb3;

            // analytic qlayer: products of cos (depth-2 trees)
            float cz0 = __cosf(z0), cz1 = __cosf(z1), cz2 = __cosf(z2), cz3 = __cosf(z3);
            float t01 = cz0 * cz1;
            float t23 = cz2 * cz3;
            float q0 = cz1 * t23;        // wire0: z1 z2 z3
            float q1 = t01;              // wire1: z0 z1
            float q2 = t01 * cz2;        // wire2: z0 z1 z2
            float q3 = t01 * t23;        // wire3: z0 z1 z2 z3

            float a0 = act_sb(q0, kk, scl, bia);
            float a1 = act_sb(q1, kk, scl, bia);
            float a2 = act_sb(q2, kk, scl, bia);
            float a3 = act_sb(q3, kk, scl, bia);

            // exchange activated gate vectors across the quad (DPP broadcasts)
            float f0 = qb0(a0), f1 = qb0(a1), f2 = qb0(a2), f3 = qb0(a3);
            float i0 = qb1(a0), i1 = qb1(a1), i2 = qb1(a2), i3 = qb1(a3);
            float u0 = qb2(a0), u1 = qb2(a1), u2 = qb2(a2), u3 = qb2(a3);
            float o0 = qb3(a0), o1 = qb3(a1), o2 = qb3(a2), o3 = qb3(a3);

            c0 = fmaf(f0, c0, i0 * u0);
            c1 = fmaf(f1, c1, i1 * u1);
            c2 = fmaf(f2, c2, i2 * u2);
            c3 = fmaf(f3, c3, i3 * u3);

            h0 = o0 * tanh_fast(c0);
            h1 = o1 * tanh_fast(c1);
            h2 = o2 * tanh_fast(c2);
            h3 = o3 * tanh_fast(c3);

            float hv = (g == 0) ? h0 : (g == 1) ? h1 : (g == 2) ? h2 : h3;
            out[t * (BATCH * 4) + b * 4 + g] = hv;
        }
    }

    float hv = (g == 0) ? h0 : (g == 1) ? h1 : (g == 2) ? h2 : h3;
    float cv = (g == 0) ? c0 : (g == 1) ? c1 : (g == 2) ? c2 : c3;
    hx_out[b * 4 + g] = hv;
    cx_out[b * 4 + g] = cv;
}

// ---------------------------------------------------------------------------
extern "C" void kernel_launch(void* const* d_in, const int* in_sizes, int n_in,
                              void* d_out, int out_size, void* d_ws, size_t ws_size,
                              hipStream_t stream)
{
    (void)in_sizes; (void)n_in; (void)out_size; (void)ws_size;

    const float* x   = (const float*)d_in[0];
    const float* Wf  = (const float*)d_in[1];
    const float* Wi  = (const float*)d_in[2];
    const float* Wu  = (const float*)d_in[3];
    const float* Wo  = (const float*)d_in[4];
    const float* thf = (const float*)d_in[5];
    const float* thi = (const float*)d_in[6];
    const float* thu = (const float*)d_in[7];
    const float* tho = (const float*)d_in[8];

    float* xp  = (float*)d_ws;          // [NROWS][16] = 8 MiB
    float* out = (float*)d_out;         // outputs [T,B,4] ++ hx [B,4] ++ cx [B,4]

    xproj_kernel<<<NROWS / 256, 256, 0, stream>>>(x, Wf, Wi, Wu, Wo, thf, thi, thu, tho, xp);
    recur_kernel<<<BATCH / 16, 64, 0, stream>>>(xp, Wf, Wi, Wu, Wo, out);
}

// Round 14
// 282.590 us; speedup vs baseline: 1.0958x; 1.0150x over previous
//
#include <hip/hip_runtime.h>

#define TSTEPS 256
#define BATCH  512
#define DIN    256
#define NROWS  (TSTEPS * BATCH)

// ---------------------------------------------------------------------------
// Kernel 1: Xproj[row][g*4+w] = theta_g[w] + sum_d x[row][d] * W_g[w][d]
// UNCHANGED from R4 (passed verify; <77us, not yet isolated in top-5).
// ---------------------------------------------------------------------------
__global__ __launch_bounds__(256) void xproj_kernel(
    const float* __restrict__ x,
    const float* __restrict__ Wf, const float* __restrict__ Wi,
    const float* __restrict__ Wu, const float* __restrict__ Wo,
    const float* __restrict__ thf, const float* __restrict__ thi,
    const float* __restrict__ thu, const float* __restrict__ tho,
    float* __restrict__ xp)
{
    __shared__ __align__(16) float sW[16][DIN];
    const int tid = threadIdx.x;

    for (int i = tid; i < 1024; i += 256) { int w = i >> 8, d = i & 255; sW[ 0 + w][d] = Wf[w * 260 + d]; }
    for (int i = tid; i < 1024; i += 256) { int w = i >> 8, d = i & 255; sW[ 4 + w][d] = Wi[w * 260 + d]; }
    for (int i = tid; i < 1024; i += 256) { int w = i >> 8, d = i & 255; sW[ 8 + w][d] = Wu[w * 260 + d]; }
    for (int i = tid; i < 1024; i += 256) { int w = i >> 8, d = i & 255; sW[12 + w][d] = Wo[w * 260 + d]; }
    __syncthreads();

    const int row = blockIdx.x * 256 + tid;
    const float4* xr = (const float4*)(x + (size_t)row * DIN);

    float acc[16];
    #pragma unroll
    for (int w = 0; w < 4; ++w) acc[ 0 + w] = thf[w];
    #pragma unroll
    for (int w = 0; w < 4; ++w) acc[ 4 + w] = thi[w];
    #pragma unroll
    for (int w = 0; w < 4; ++w) acc[ 8 + w] = thu[w];
    #pragma unroll
    for (int w = 0; w < 4; ++w) acc[12 + w] = tho[w];

    #pragma unroll 4
    for (int cc = 0; cc < 64; ++cc) {
        float4 xv = xr[cc];
        #pragma unroll
        for (int k = 0; k < 16; ++k) {
            float4 wv = *(const float4*)&sW[k][cc * 4];
            acc[k] = fmaf(xv.w, wv.w, fmaf(xv.z, wv.z, fmaf(xv.y, wv.y, fmaf(xv.x, wv.x, acc[k]))));
        }
    }

    float4* op = (float4*)(xp + (size_t)row * 16);
    op[0] = make_float4(acc[ 0], acc[ 1], acc[ 2], acc[ 3]);
    op[1] = make_float4(acc[ 4], acc[ 5], acc[ 6], acc[ 7]);
    op[2] = make_float4(acc[ 8], acc[ 9], acc[10], acc[11]);
    op[3] = make_float4(acc[12], acc[13], acc[14], acc[15]);
}

// ---------------------------------------------------------------------------
// Kernel 2: sequential LSTM scan. 4 lanes per batch element (one per gate).
// R5: 8-deep register prefetch ring (fixed exposed HBM latency, 91->~68us).
// R9: cut transcendentals 20 -> 9 per lane-step (R8 inference: single-wave
// issue-bound, trans ~16cy issue each dominated):
//   - all 4 gate activations via one uniform Pade[5/4] tanh,
//     a = B*T(K*q)+A  (f/i/o: sigmoid = 0.5+0.5*T(q/2); u: T(q))
//   - tanh(c) computed ONCE per lane (own wire) instead of 4x duplicated;
//     h broadcast via 4 DPP. |c| <= 2.07 (fixed point of gate bounds), and
//     Pade[5/4] err <= 3.3e-5 on [-2.1,2.1] (hand-verified at 1, 2, 2.1).
// ---------------------------------------------------------------------------
__device__ __forceinline__ float qb0(float v) { return __int_as_float(__builtin_amdgcn_mov_dpp(__float_as_int(v), 0x00, 0xf, 0xf, true)); }
__device__ __forceinline__ float qb1(float v) { return __int_as_float(__builtin_amdgcn_mov_dpp(__float_as_int(v), 0x55, 0xf, 0xf, true)); }
__device__ __forceinline__ float qb2(float v) { return __int_as_float(__builtin_amdgcn_mov_dpp(__float_as_int(v), 0xaa, 0xf, 0xf, true)); }
__device__ __forceinline__ float qb3(float v) { return __int_as_float(__builtin_amdgcn_mov_dpp(__float_as_int(v), 0xff, 0xf, 0xf, true)); }

__device__ __forceinline__ float fast_rcp(float x) { return __builtin_amdgcn_rcpf(x); }

// Pade[5/4]: tanh(x) ~= x*(945 + 105x^2 + x^4) / (945 + 420x^2 + 15x^4)
__device__ __forceinline__ float pade_tanh(float x) {
    float t = x * x;
    float num = x * fmaf(t, t + 105.0f, 945.0f);
    float den = fmaf(t, fmaf(t, 15.0f, 420.0f), 945.0f);
    return num * fast_rcp(den);
}

__global__ __launch_bounds__(64) void recur_kernel(
    const float* __restrict__ xp,
    const float* __restrict__ Wf, const float* __restrict__ Wi,
    const float* __restrict__ Wu, const float* __restrict__ Wo,
    float* __restrict__ out)
{
    const int tid = threadIdx.x;
    const int g   = tid & 3;                   // gate: 0=f 1=i 2=u 3=o
    const int b   = blockIdx.x * 16 + (tid >> 2);

    const float* Wg = (g == 0) ? Wf : (g == 1) ? Wi : (g == 2) ? Wu : Wo;
    const float4 w0 = *(const float4*)(Wg + 0 * 260 + 256);
    const float4 w1 = *(const float4*)(Wg + 1 * 260 + 256);
    const float4 w2 = *(const float4*)(Wg + 2 * 260 + 256);
    const float4 w3 = *(const float4*)(Wg + 3 * 260 + 256);

    // act = B * pade_tanh(K*q) + A ; f/i/o: sigmoid, u: tanh
    const float K = (g == 2) ? 1.0f : 0.5f;
    const float A = (g == 2) ? 0.0f : 0.5f;
    const float B = (g == 2) ? 1.0f : 0.5f;

    float h0 = 0.f, h1 = 0.f, h2 = 0.f, h3 = 0.f;
    float c0 = 0.f, c1 = 0.f, c2 = 0.f, c3 = 0.f;
    float hg = 0.f, cg = 0.f;                  // own-wire state (wire = g)

    const float4* xpv = (const float4*)xp;     // 4 float4 per (t,b) row-slot
    const int idx = b * 4 + g;                 // this lane's gate-vector slot

    // --- 8-deep prefetch ring (static indices only -> registers) ---
    float4 buf[8];
    #pragma unroll
    for (int j = 0; j < 8; ++j) buf[j] = xpv[(size_t)j * (BATCH * 4) + idx];

    float* hx_out = out + (size_t)TSTEPS * BATCH * 4;
    float* cx_out = hx_out + BATCH * 4;

    for (int t0 = 0; t0 < TSTEPS; t0 += 8) {
        #pragma unroll
        for (int j = 0; j < 8; ++j) {
            const int t = t0 + j;
            float4 xv = buf[j];
            int tl = t + 8; tl = (tl > TSTEPS - 1) ? (TSTEPS - 1) : tl;
            buf[j] = xpv[(size_t)tl * (BATCH * 4) + idx];

            // z = x-part(+theta) + h @ Wh.T  (depth-3 tree)
            float za0 = fmaf(h1, w0.y, fmaf(h0, w0.x, xv.x));
            float zb0 = fmaf(h3, w0.w, h2 * w0.z);
            float za1 = fmaf(h1, w1.y, fmaf(h0, w1.x, xv.y));
            float zb1 = fmaf(h3, w1.w, h2 * w1.z);
            float za2 = fmaf(h1, w2.y, fmaf(h0, w2.x, xv.z));
            float zb2 = fmaf(h3, w2.w, h2 * w2.z);
            float za3 = fmaf(h1, w3.y, fmaf(h0, w3.x, xv.w));
            float zb3 = fmaf(h3, w3.w, h2 * w3.z);
            float z0 = za0 + zb0, z1 = za1 + zb1, z2 = za2 + zb2, z3 = za3 + zb3;

            // analytic qlayer: products of cos
            float cz0 = __cosf(z0), cz1 = __cosf(z1), cz2 = __cosf(z2), cz3 = __cosf(z3);
            float t01 = cz0 * cz1;
            float t23 = cz2 * cz3;
            float q0 = cz1 * t23;        // wire0: z1 z2 z3
            float q1 = t01;              // wire1: z0 z1
            float q2 = t01 * cz2;        // wire2: z0 z1 z2
            float q3 = t01 * t23;        // wire3: z0 z1 z2 z3

            // uniform Pade activation, per-lane constants
            float a0 = fmaf(B, pade_tanh(K * q0), A);
            float a1 = fmaf(B, pade_tanh(K * q1), A);
            float a2 = fmaf(B, pade_tanh(K * q2), A);
            float a3 = fmaf(B, pade_tanh(K * q3), A);

            // exchange activated gate vectors across the quad (DPP broadcasts)
            float f0 = qb0(a0), f1 = qb0(a1), f2 = qb0(a2), f3 = qb0(a3);
            float i0 = qb1(a0), i1 = qb1(a1), i2 = qb1(a2), i3 = qb1(a3);
            float u0 = qb2(a0), u1 = qb2(a1), u2 = qb2(a2), u3 = qb2(a3);
            float o0 = qb3(a0), o1 = qb3(a1), o2 = qb3(a2), o3 = qb3(a3);

            // cell update (replicated: all lanes need all c for next selects)
            c0 = fmaf(f0, c0, i0 * u0);
            c1 = fmaf(f1, c1, i1 * u1);
            c2 = fmaf(f2, c2, i2 * u2);
            c3 = fmaf(f3, c3, i3 * u3);

            // own-wire tanh ONCE per lane; broadcast h across the quad
            cg = (g & 2) ? ((g & 1) ? c3 : c2) : ((g & 1) ? c1 : c0);
            float og = (g & 2) ? ((g & 1) ? o3 : o2) : ((g & 1) ? o1 : o0);
            hg = og * pade_tanh(cg);

            h0 = qb0(hg); h1 = qb1(hg); h2 = qb2(hg); h3 = qb3(hg);

            out[t * (BATCH * 4) + b * 4 + g] = hg;   // lane g owns wire g
        }
    }

    hx_out[b * 4 + g] = hg;
    cx_out[b * 4 + g] = cg;
}

// ---------------------------------------------------------------------------
extern "C" void kernel_launch(void* const* d_in, const int* in_sizes, int n_in,
                              void* d_out, int out_size, void* d_ws, size_t ws_size,
                              hipStream_t stream)
{
    (void)in_sizes; (void)n_in; (void)out_size; (void)ws_size;

    const float* x   = (const float*)d_in[0];
    const float* Wf  = (const float*)d_in[1];
    const float* Wi  = (const float*)d_in[2];
    const float* Wu  = (const float*)d_in[3];
    const float* Wo  = (const float*)d_in[4];
    const float* thf = (const float*)d_in[5];
    const float* thi = (const float*)d_in[6];
    const float* thu = (const float*)d_in[7];
    const float* tho = (const float*)d_in[8];

    float* xp  = (float*)d_ws;          // [NROWS][16] = 8 MiB
    float* out = (float*)d_out;         // outputs [T,B,4] ++ hx [B,4] ++ cx [B,4]

    xproj_kernel<<<NROWS / 256, 256, 0, stream>>>(x, Wf, Wi, Wu, Wo, thf, thi, thu, tho, xp);
    recur_kernel<<<BATCH / 16, 64, 0, stream>>>(xp, Wf, Wi, Wu, Wo, out);
}